// Round 14
// baseline (221.378 us; speedup 1.0000x reference)
//
#include <hip/hip_runtime.h>
#include <hip/hip_bf16.h>

// PCGraphConv: iterative predictive-coding message passing.
// N_V=2000, N_SENS=784, N_E=500000, BATCH=32, T=5, lr=0.1.
// R13: R12's proven scan-chain W-build + wave-per-tile GEMMs.
//  - GEMMs: 64-thread blocks, one wave owns one weight tile, K=63 chunks,
//    BOTH batch-halves as dual accumulator chains (weight loaded once),
//    no LDS reduce, no syncthreads, all lanes active in epilogue.
//    (R12/R13 A/B showed graph dispatch boundaries are cheap ~1-2us; the
//    cost was in the 4-wave split + h-duplicated weight reads ~7us/gemm.)
//  - build: cnt -> scan_a -> scan_b -> place -> build -> trB (proven 172us).
//  - k_init coalesced; sensory out rows in init; interior out in final gemm2.
// Fallback: proven R4 CSR path if ws too small.

#define N_V     2000
#define N_SENS  784
#define N_INT   (N_V - N_SENS)   // 1216
#define N_E     500000
#define T_STEPS 5
#define LR_VAL  0.1f
#define NVB     (N_V * 32)       // 64000
#define NVH     (N_V * 16)       // 32000
#define KP      2016             // padded K (63 chunks of 32)
#define NCH     63               // K chunks
#define NT1     125              // dst tiles (125*16 = 2000)
#define NT2     76               // interior src tiles (76*16 = 1216)
#define FRAG_N  (2 * NCH * 64 * 8)   // 64512 u16 per A-frag table
#define NBLK    250              // sort blocks
#define EPB     2000             // edges per sort block

typedef float  f32x4 __attribute__((ext_vector_type(4)));
typedef short  s16x8 __attribute__((ext_vector_type(8)));

__device__ __forceinline__ float bits_to_f32(unsigned u) {
    union { unsigned u; float f; } c; c.u = u; return c.f;
}
__device__ __forceinline__ unsigned f32_to_bits(float f) {
    union { float f; unsigned u; } c; c.f = f; return c.u;
}
__device__ __forceinline__ unsigned short f32_to_bf16(float f) {
    unsigned u = f32_to_bits(f);
    return (unsigned short)((u + 0x7FFFu + ((u >> 16) & 1u)) >> 16);  // RNE
}
__device__ __forceinline__ float bf16_to_f32(unsigned short s) {
    return bits_to_f32((unsigned)s << 16);
}

// A-fragment u16 index for element (k, b) of fx/err tables (m = b&15).
__device__ __forceinline__ int aposKB(int k, int b) {
    int c = k >> 5, q = (k >> 3) & 3, j = k & 7;
    int h = b >> 4, m = b & 15;
    return (((h * NCH + c) * 64) + q * 16 + m) * 8 + j;
}

// ------------------------- dense/MFMA path -------------------------------

// histogram edges by dst-tile; cnt_g layout [tile][block]; + zero frag pads
__global__ __launch_bounds__(256) void k_cnt(const int* __restrict__ dst,
                                             int* __restrict__ cnt_g,
                                             unsigned short* __restrict__ fxA,
                                             unsigned short* __restrict__ errA) {
    __shared__ int cnt[NT1];
    int b = blockIdx.x;
    {   // zero pad slots k in [2000,2016) of both frag tables
        int t = b * 256 + threadIdx.x;
        if (t < 16 * 32) {
            int k = 2000 + (t >> 5), bb = t & 31;
            fxA[aposKB(k, bb)] = 0;
            errA[aposKB(k, bb)] = 0;
        }
    }
    for (int i = threadIdx.x; i < NT1; i += 256) cnt[i] = 0;
    __syncthreads();
    int base = b * EPB;
    for (int e = base + threadIdx.x; e < base + EPB; e += 256)
        atomicAdd(&cnt[dst[e] >> 4], 1);
    __syncthreads();
    for (int t = threadIdx.x; t < NT1; t += 256)
        cnt_g[t * 256 + b] = cnt[t];
}

// per-tile exclusive scan over blocks; totals[t] = tile edge count
__global__ __launch_bounds__(256) void k_scan_a(const int* __restrict__ cnt_g,
                                                int* __restrict__ base_g,
                                                int* __restrict__ totals) {
    __shared__ int sh[256];
    int t = blockIdx.x, tid = threadIdx.x;
    int v = (tid < NBLK) ? cnt_g[t * 256 + tid] : 0;
    sh[tid] = v;
    __syncthreads();
    for (int off = 1; off < 256; off <<= 1) {
        int x = (tid >= off) ? sh[tid - off] : 0;
        __syncthreads();
        sh[tid] += x;
        __syncthreads();
    }
    if (tid < NBLK) base_g[t * 256 + tid] = sh[tid] - v;   // exclusive
    if (tid == 255) totals[t] = sh[255];
}

// scan tile totals -> tile_start[0..125]
__global__ void k_scan_b(const int* __restrict__ totals, int* __restrict__ tile_start) {
    if (threadIdx.x == 0 && blockIdx.x == 0) {
        int acc = 0;
        for (int t = 0; t < NT1; ++t) { tile_start[t] = acc; acc += totals[t]; }
        tile_start[NT1] = acc;
    }
}

// place edges into sorted order: pk = (bf16w<<16)|(row4<<11)|src
__global__ __launch_bounds__(256) void k_place(
        const int* __restrict__ src, const int* __restrict__ dst,
        const float* __restrict__ w, const int* __restrict__ base_g,
        const int* __restrict__ tile_start, unsigned* __restrict__ pk_g) {
    __shared__ int cur[NT1];
    int b = blockIdx.x;
    for (int t = threadIdx.x; t < NT1; t += 256)
        cur[t] = tile_start[t] + base_g[t * 256 + b];
    __syncthreads();
    int base = b * EPB;
    for (int e = base + threadIdx.x; e < base + EPB; e += 256) {
        int d = dst[e];
        unsigned pk = ((unsigned)f32_to_bf16(w[e]) << 16)
                    | ((unsigned)(d & 15) << 11) | (unsigned)src[e];
        int p = atomicAdd(&cur[d >> 4], 1);
        pk_g[p] = pk;
    }
}

// build WAbf fragments + dense bf16 WAd from sorted edges.
// 250 blocks: tile = bx>>1, half = bx&1 (rows half*8 .. half*8+7).
__global__ __launch_bounds__(256) void k_build(
        const unsigned* __restrict__ pk_g, const int* __restrict__ tile_start,
        uint4* __restrict__ WAbf4, unsigned short* __restrict__ WAd) {
    __shared__ float acc[8][KP];   // 64.5 KB
    int tile = blockIdx.x >> 1, half = blockIdx.x & 1;
    for (int i = threadIdx.x; i < 8 * KP / 4; i += 256)
        ((float4*)&acc[0][0])[i] = make_float4(0.f, 0.f, 0.f, 0.f);
    __syncthreads();
    int beg = tile_start[tile], end = tile_start[tile + 1];
    for (int e = beg + threadIdx.x; e < end; e += 256) {
        unsigned pk = pk_g[e];
        int row = (int)((pk >> 11) & 15u);
        if ((row >> 3) == half)
            atomicAdd(&acc[row & 7][pk & 0x7FFu], bf16_to_f32((unsigned short)(pk >> 16)));
    }
    __syncthreads();
    for (int i = threadIdx.x; i < 8 * 252; i += 256) {
        int rr = i / 252, g = i - rr * 252;
        int c = g >> 2, q = g & 3;
        int col = g * 8;
        unsigned short r[8];
        #pragma unroll
        for (int j = 0; j < 8; ++j) r[j] = f32_to_bf16(acc[rr][col + j]);
        uint4 val = *(const uint4*)r;
        int m = half * 8 + rr;
        WAbf4[((tile * NCH + c) * 64) + q * 16 + m] = val;
        *(uint4*)(WAd + (size_t)(tile * 16 + m) * KP + col) = val;
    }
}

// WBf[((tile*63+c)*64+l)*8+j] = WAd[c*32+(l>>4)*8+j][784+tile*16+(l&15)]
__global__ void k_trB(const unsigned short* __restrict__ WAd, uint4* __restrict__ WBf4) {
    int t = blockIdx.x * blockDim.x + threadIdx.x;
    if (t < NT2 * NCH * 64) {
        int tile = t / (NCH * 64);
        int rem = t - tile * (NCH * 64);
        int c = rem >> 6, l = rem & 63;
        int jcol = N_SENS + tile * 16 + (l & 15);
        int k0 = c * 32 + (l >> 4) * 8;
        unsigned short r[8];
        #pragma unroll
        for (int j = 0; j < 8; ++j)
            r[j] = (k0 + j < N_V) ? WAd[(size_t)(k0 + j) * KP + jcol] : (unsigned short)0;
        WBf4[t] = *(const uint4*)r;
    }
}

// coalesced init: reads vin[t] linearly; writes v_cur/fxA scattered (L2-hot);
// sensory out rows (constant across steps) written here, coalesced.
__global__ void k_init(const float* __restrict__ vin, float* __restrict__ v,
                       unsigned short* __restrict__ fxA, float* __restrict__ out) {
    int t = blockIdx.x * blockDim.x + threadIdx.x;
    if (t < NVB) {
        float x = vin[t];
        int b = t / N_V;
        int i = t - b * N_V;
        v[(i << 5) + b] = x;
        fxA[aposKB(i, b)] = f32_to_bf16(tanhf(x));
        if (i < N_SENS) out[t] = x;
    }
}

// GEMM1: err = v - fx.WA^T ; one wave per dst-tile, both batch halves.
// 125 blocks x 64 threads; dual accumulators share one weight load.
__global__ __launch_bounds__(64) void k_gemm1(
        const uint4* __restrict__ WAbf4, const uint4* __restrict__ fxA4,
        const float* __restrict__ v_cur, unsigned short* __restrict__ errA) {
    int tile = blockIdx.x;
    int l = threadIdx.x;
    const uint4* bp  = WAbf4 + (size_t)tile * NCH * 64 + l;
    const uint4* a0p = fxA4 + l;
    const uint4* a1p = fxA4 + (size_t)NCH * 64 + l;
    f32x4 acc0 = {0.f, 0.f, 0.f, 0.f}, acc1 = {0.f, 0.f, 0.f, 0.f};
    #pragma unroll 7
    for (int c = 0; c < NCH; ++c) {
        uint4 bfrag = bp[c * 64];
        uint4 a0 = a0p[c * 64];
        uint4 a1 = a1p[c * 64];
        acc0 = __builtin_amdgcn_mfma_f32_16x16x32_bf16(
                   *(s16x8*)&a0, *(s16x8*)&bfrag, acc0, 0, 0, 0);
        acc1 = __builtin_amdgcn_mfma_f32_16x16x32_bf16(
                   *(s16x8*)&a1, *(s16x8*)&bfrag, acc1, 0, 0, 0);
    }
    int i = tile * 16 + (l & 15);
    int q = l >> 4;
    int c2 = i >> 5, q2 = (i >> 3) & 3, j2 = i & 7;
    #pragma unroll
    for (int h = 0; h < 2; ++h) {
        f32x4 acc = h ? acc1 : acc0;
        const float4 v4 = *(const float4*)(v_cur + (i << 5) + h * 16 + q * 4);
        int base = ((h * NCH + c2) * 64 + q2 * 16) * 8 + j2;
        errA[base + (q * 4 + 0) * 8] = f32_to_bf16(v4.x - acc[0]);
        errA[base + (q * 4 + 1) * 8] = f32_to_bf16(v4.y - acc[1]);
        errA[base + (q * 4 + 2) * 8] = f32_to_bf16(v4.z - acc[2]);
        errA[base + (q * 4 + 3) * 8] = f32_to_bf16(v4.w - acc[3]);
    }
}

// GEMM2: back = err.WB^T ; one wave per interior tile, both halves; fused
// v update + tanh + fx repack; final: also store interior out rows.
__global__ __launch_bounds__(64) void k_gemm2(
        const uint4* __restrict__ WBf4, const uint4* __restrict__ errA4,
        unsigned short* __restrict__ errA, unsigned short* __restrict__ fxA,
        float* __restrict__ v_cur, float* __restrict__ out, int final_step) {
    int tile = blockIdx.x;
    int l = threadIdx.x;
    const uint4* bp  = WBf4 + (size_t)tile * NCH * 64 + l;
    const uint4* a0p = errA4 + l;
    const uint4* a1p = errA4 + (size_t)NCH * 64 + l;
    f32x4 acc0 = {0.f, 0.f, 0.f, 0.f}, acc1 = {0.f, 0.f, 0.f, 0.f};
    #pragma unroll 7
    for (int c = 0; c < NCH; ++c) {
        uint4 bfrag = bp[c * 64];
        uint4 a0 = a0p[c * 64];
        uint4 a1 = a1p[c * 64];
        acc0 = __builtin_amdgcn_mfma_f32_16x16x32_bf16(
                   *(s16x8*)&a0, *(s16x8*)&bfrag, acc0, 0, 0, 0);
        acc1 = __builtin_amdgcn_mfma_f32_16x16x32_bf16(
                   *(s16x8*)&a1, *(s16x8*)&bfrag, acc1, 0, 0, 0);
    }
    int j = N_SENS + tile * 16 + (l & 15);
    int q = l >> 4;
    int c2 = j >> 5, q2 = (j >> 3) & 3, j2 = j & 7;
    #pragma unroll
    for (int h = 0; h < 2; ++h) {
        f32x4 acc = h ? acc1 : acc0;
        float4 v4 = *(const float4*)(v_cur + (j << 5) + h * 16 + q * 4);
        int base = ((h * NCH + c2) * 64 + q2 * 16) * 8 + j2;
        float vv[4] = {v4.x, v4.y, v4.z, v4.w};
        #pragma unroll
        for (int r = 0; r < 4; ++r) {
            float e0 = bf16_to_f32(errA[base + (q * 4 + r) * 8]);
            float fxv = tanhf(vv[r]);
            float vn = vv[r] - LR_VAL * (e0 - (1.f - fxv * fxv) * acc[r]);
            vv[r] = vn;
            fxA[base + (q * 4 + r) * 8] = f32_to_bf16(tanhf(vn));
        }
        float4 o = {vv[0], vv[1], vv[2], vv[3]};
        *(float4*)(v_cur + (j << 5) + h * 16 + q * 4) = o;
        if (final_step) {
            #pragma unroll
            for (int r = 0; r < 4; ++r) {
                int b = h * 16 + q * 4 + r;
                out[b * N_V + j] = vv[r];
            }
        }
    }
}

// ------------------------- fallback path (R4 CSR, proven) ----------------

__global__ void k_zero_i32(int* a, int n) {
    int t = blockIdx.x * blockDim.x + threadIdx.x;
    if (t < n) a[t] = 0;
}

__global__ void k_hist(const int* __restrict__ src, const int* __restrict__ dst,
                       int* cnt_dst, int* cnt_src) {
    int e = blockIdx.x * blockDim.x + threadIdx.x;
    if (e < N_E) {
        atomicAdd(&cnt_dst[dst[e]], 1);
        atomicAdd(&cnt_src[src[e]], 1);
    }
}

__global__ __launch_bounds__(1024) void k_scan(int* cnt_a, int* rp_a,
                                               int* cnt_b, int* rp_b) {
    __shared__ int sh[1024];
    int t = threadIdx.x;
    for (int pass = 0; pass < 2; ++pass) {
        int* cnt = pass ? cnt_b : cnt_a;
        int* rp  = pass ? rp_b  : rp_a;
        int i0 = 2 * t, i1 = 2 * t + 1;
        int c0 = (i0 < N_V) ? cnt[i0] : 0;
        int c1 = (i1 < N_V) ? cnt[i1] : 0;
        __syncthreads();
        sh[t] = c0 + c1;
        __syncthreads();
        for (int off = 1; off < 1024; off <<= 1) {
            int v = (t >= off) ? sh[t - off] : 0;
            __syncthreads();
            sh[t] += v;
            __syncthreads();
        }
        int incl = sh[t];
        int e0 = incl - (c0 + c1);
        int e1 = e0 + c0;
        if (i0 <= N_V) rp[i0] = e0;
        if (i1 <= N_V) rp[i1] = e1;
        if (i0 < N_V) cnt[i0] = e0;
        if (i1 < N_V) cnt[i1] = e1;
    }
}

__global__ void k_scatter(const int* __restrict__ src, const int* __restrict__ dst,
                          const float* __restrict__ w,
                          int* cur_dst, int* cur_src,
                          unsigned* __restrict__ pk_dst, unsigned* __restrict__ pk_src) {
    int e = blockIdx.x * blockDim.x + threadIdx.x;
    if (e < N_E) {
        int s = src[e], d = dst[e];
        unsigned wbits = (unsigned)f32_to_bf16(w[e]);
        int p = atomicAdd(&cur_dst[d], 1);
        pk_dst[p] = (wbits << 16) | (unsigned)s;
        int q = atomicAdd(&cur_src[s], 1);
        pk_src[q] = (wbits << 16) | (unsigned)d;
    }
}

__global__ void k_cast_in(const float* __restrict__ vin, float* __restrict__ v) {
    int t = blockIdx.x * blockDim.x + threadIdx.x;
    if (t < NVB) {
        int i = t >> 5, b = t & 31;
        v[t] = vin[b * N_V + i];
    }
}

__global__ void k_fx_csr(const float* __restrict__ v, unsigned short* __restrict__ fx) {
    int t = blockIdx.x * blockDim.x + threadIdx.x;
    if (t < NVB) {
        int i = t >> 5, b = t & 31;
        int h = b >> 4, b16 = b & 15;
        fx[h * NVH + i * 16 + b16] = f32_to_bf16(tanhf(v[t]));
    }
}

__global__ __launch_bounds__(256) void k_pred_err(
        const float* __restrict__ v, const unsigned short* __restrict__ fx,
        const int* __restrict__ rp, const unsigned* __restrict__ pk,
        unsigned short* __restrict__ err) {
    __shared__ unsigned short tab[NVH];
    int h  = blockIdx.x / 250;
    int vg = blockIdx.x % 250;
    {
        const uint4* g = (const uint4*)(fx + h * NVH);
        uint4* l = (uint4*)tab;
        for (int i = threadIdx.x; i < NVH / 8; i += 256) l[i] = g[i];
    }
    __syncthreads();
    int wave = threadIdx.x >> 6;
    int lane = threadIdx.x & 63;
    int b16 = lane & 15, epar = lane >> 4;
    for (int k = 0; k < 2; ++k) {
        int vid = vg * 8 + wave * 2 + k;
        int beg = rp[vid], end = rp[vid + 1];
        float sum = 0.f;
        for (int e = beg + epar; e < end; e += 4) {
            unsigned p = pk[e];
            float w = bits_to_f32(p & 0xFFFF0000u);
            int nb = (int)(p & 0xFFFFu);
            sum += w * bf16_to_f32(tab[nb * 16 + b16]);
        }
        sum += __shfl_xor(sum, 16, 64);
        sum += __shfl_xor(sum, 32, 64);
        if (epar == 0) {
            float vo = v[(vid << 5) + h * 16 + b16];
            err[h * NVH + vid * 16 + b16] = f32_to_bf16(vo - sum);
        }
    }
}

__global__ __launch_bounds__(256) void k_back_upd(
        const unsigned short* __restrict__ fx, const unsigned short* __restrict__ err,
        const int* __restrict__ rp, const unsigned* __restrict__ pk,
        float* __restrict__ v) {
    __shared__ unsigned short tab[NVH];
    int h  = blockIdx.x / 152;
    int vg = blockIdx.x % 152;
    {
        const uint4* g = (const uint4*)(err + h * NVH);
        uint4* l = (uint4*)tab;
        for (int i = threadIdx.x; i < NVH / 8; i += 256) l[i] = g[i];
    }
    __syncthreads();
    int wave = threadIdx.x >> 6;
    int lane = threadIdx.x & 63;
    int b16 = lane & 15, epar = lane >> 4;
    for (int k = 0; k < 2; ++k) {
        int vid = N_SENS + vg * 8 + wave * 2 + k;
        if (vid >= N_V) continue;
        int beg = rp[vid], end = rp[vid + 1];
        float sum = 0.f;
        for (int e = beg + epar; e < end; e += 4) {
            unsigned p = pk[e];
            float w = bits_to_f32(p & 0xFFFF0000u);
            int nb = (int)(p & 0xFFFFu);
            sum += w * bf16_to_f32(tab[nb * 16 + b16]);
        }
        sum += __shfl_xor(sum, 16, 64);
        sum += __shfl_xor(sum, 32, 64);
        if (epar == 0) {
            float e0  = bf16_to_f32(tab[vid * 16 + b16]);
            float fxv = bf16_to_f32(fx[h * NVH + vid * 16 + b16]);
            float dv = e0 - (1.f - fxv * fxv) * sum;
            v[(vid << 5) + h * 16 + b16] -= LR_VAL * dv;
        }
    }
}

__global__ void k_out_fb(const float* __restrict__ v, float* __restrict__ out) {
    int t = blockIdx.x * blockDim.x + threadIdx.x;
    if (t < NVB) {
        int b = t / N_V;
        int i = t - b * N_V;
        out[t] = v[(i << 5) + b];
    }
}

// ------------------------- host -----------------------------------------

extern "C" void kernel_launch(void* const* d_in, const int* in_sizes, int n_in,
                              void* d_out, int out_size, void* d_ws, size_t ws_size,
                              hipStream_t stream) {
    const float* vals = (const float*)d_in[0];
    const float* wts  = (const float*)d_in[1];
    const int* ei = (const int*)d_in[2];
    const int* src = ei;
    const int* dst = ei + N_E;
    float* out = (float*)d_out;

    const int EB = (N_E + 255) / 256;

    // ws layout: pk_g | cnt_g | base_g | totals | tile_start | WAd | WAbf | WBf
    //            | fxA | errA | v_cur   (~23.5 MB)
    const size_t WABF_T = (size_t)NT1 * NCH * 64;  // uint4 count
    const size_t WBF_T  = (size_t)NT2 * NCH * 64;
    const size_t WAD_N  = (size_t)N_V * KP;
    const size_t need = (size_t)N_E * 4 + 2 * NT1 * 256 * 4 + 512 * 4
                      + WAD_N * 2 + WABF_T * 16 + WBF_T * 16
                      + 2 * (size_t)FRAG_N * 2 + NVB * 4 + 256;

    if (ws_size >= need) {
        unsigned* pk_g = (unsigned*)d_ws;
        int* cnt_g  = (int*)(pk_g + N_E);
        int* base_g = cnt_g + NT1 * 256;
        int* totals = base_g + NT1 * 256;
        int* tile_start = totals + 128;
        unsigned short* WAd = (unsigned short*)(tile_start + 384);
        uint4* WAbf4 = (uint4*)(WAd + WAD_N);
        uint4* WBf4  = WAbf4 + WABF_T;
        unsigned short* fxA  = (unsigned short*)(WBf4 + WBF_T);
        unsigned short* errA = fxA + FRAG_N;
        float* v_cur = (float*)(errA + FRAG_N);

        k_cnt<<<NBLK, 256, 0, stream>>>(dst, cnt_g, fxA, errA);
        k_scan_a<<<NT1, 256, 0, stream>>>(cnt_g, base_g, totals);
        k_scan_b<<<1, 64, 0, stream>>>(totals, tile_start);
        k_place<<<NBLK, 256, 0, stream>>>(src, dst, wts, base_g, tile_start, pk_g);
        k_build<<<2 * NT1, 256, 0, stream>>>(pk_g, tile_start, WAbf4, WAd);
        k_trB<<<(int)((WBF_T + 255) / 256), 256, 0, stream>>>(WAd, WBf4);
        k_init<<<250, 256, 0, stream>>>(vals, v_cur, fxA, out);

        for (int t = 0; t < T_STEPS; ++t) {
            k_gemm1<<<NT1, 64, 0, stream>>>(WAbf4, (const uint4*)fxA, v_cur, errA);
            k_gemm2<<<NT2, 64, 0, stream>>>(WBf4, (const uint4*)errA, errA, fxA,
                                            v_cur, out, (t == T_STEPS - 1) ? 1 : 0);
        }
    } else {
        float* v_cur = (float*)d_ws;
        unsigned short* fx_g  = (unsigned short*)(v_cur + NVB);
        unsigned short* err_g = fx_g + NVB;
        int* rp_dst  = (int*)(err_g + NVB);
        int* rp_src  = rp_dst + 2048;
        int* cur_dst = rp_src + 2048;
        int* cur_src = cur_dst + 2048;
        unsigned* pk_dst = (unsigned*)(cur_src + 2048);
        unsigned* pk_src = pk_dst + N_E;

        k_zero_i32<<<16, 256, 0, stream>>>(cur_dst, 4096);
        k_hist<<<EB, 256, 0, stream>>>(src, dst, cur_dst, cur_src);
        k_scan<<<1, 1024, 0, stream>>>(cur_dst, rp_dst, cur_src, rp_src);
        k_scatter<<<EB, 256, 0, stream>>>(src, dst, wts, cur_dst, cur_src,
                                          pk_dst, pk_src);
        k_cast_in<<<250, 256, 0, stream>>>(vals, v_cur);
        for (int t = 0; t < T_STEPS; ++t) {
            k_fx_csr<<<250, 256, 0, stream>>>(v_cur, fx_g);
            k_pred_err<<<500, 256, 0, stream>>>(v_cur, fx_g, rp_dst, pk_dst, err_g);
            k_back_upd<<<304, 256, 0, stream>>>(fx_g, err_g, rp_src, pk_src, v_cur);
        }
        k_out_fb<<<250, 256, 0, stream>>>(v_cur, out);
    }
}

// Round 15
// 171.915 us; speedup vs baseline: 1.2877x; 1.2877x over previous
//
#include <hip/hip_runtime.h>
#include <hip/hip_bf16.h>

// PCGraphConv: iterative predictive-coding message passing.
// N_V=2000, N_SENS=784, N_E=500000, BATCH=32, T=5, lr=0.1.
// CHAMPION (measured 172.1us, R12): counting-sort W-build + unrolled MFMA GEMMs.
//  - sort chain: cnt -> scan_a -> scan_b -> place (block-private ranges,
//    ~1x write amp) -> build (LDS fp32 acc[8][2016], emit WAbf frags + dense
//    bf16 WAd) -> trB (WBf frags from WAd columns).
//  - GEMMs: operand-swapped MFMA 16x16x32_bf16; 250/152 blocks x 4 waves,
//    K fully unrolled (16 iters, wave-uniform guard) -> max in-flight loads.
//    (A/B tested: wave-per-tile (221us), bucket build (178us), coop (613us),
//    redundant-scan build (365us) — all worse.)
//  - k_init coalesced; sensory out rows in init; interior out in final gemm2.
// Fallback: proven R4 CSR path if ws too small.

#define N_V     2000
#define N_SENS  784
#define N_INT   (N_V - N_SENS)   // 1216
#define N_E     500000
#define T_STEPS 5
#define LR_VAL  0.1f
#define NVB     (N_V * 32)       // 64000
#define NVH     (N_V * 16)       // 32000
#define KP      2016             // padded K (63 chunks of 32)
#define NCH     63               // K chunks
#define NT1     125              // dst tiles (125*16 = 2000)
#define NT2     76               // interior src tiles (76*16 = 1216)
#define FRAG_N  (2 * NCH * 64 * 8)   // 64512 u16 per A-frag table
#define NBLK    250              // sort blocks
#define EPB     2000             // edges per sort block

typedef float  f32x4 __attribute__((ext_vector_type(4)));
typedef short  s16x8 __attribute__((ext_vector_type(8)));

__device__ __forceinline__ float bits_to_f32(unsigned u) {
    union { unsigned u; float f; } c; c.u = u; return c.f;
}
__device__ __forceinline__ unsigned f32_to_bits(float f) {
    union { float f; unsigned u; } c; c.f = f; return c.u;
}
__device__ __forceinline__ unsigned short f32_to_bf16(float f) {
    unsigned u = f32_to_bits(f);
    return (unsigned short)((u + 0x7FFFu + ((u >> 16) & 1u)) >> 16);  // RNE
}
__device__ __forceinline__ float bf16_to_f32(unsigned short s) {
    return bits_to_f32((unsigned)s << 16);
}

// A-fragment u16 index for element (k, b) of fx/err tables (m = b&15).
__device__ __forceinline__ int aposKB(int k, int b) {
    int c = k >> 5, q = (k >> 3) & 3, j = k & 7;
    int h = b >> 4, m = b & 15;
    return (((h * NCH + c) * 64) + q * 16 + m) * 8 + j;
}

// ------------------------- dense/MFMA path -------------------------------

// histogram edges by dst-tile; cnt_g layout [tile][block]; + zero frag pads
__global__ __launch_bounds__(256) void k_cnt(const int* __restrict__ dst,
                                             int* __restrict__ cnt_g,
                                             unsigned short* __restrict__ fxA,
                                             unsigned short* __restrict__ errA) {
    __shared__ int cnt[NT1];
    int b = blockIdx.x;
    {   // zero pad slots k in [2000,2016) of both frag tables
        int t = b * 256 + threadIdx.x;
        if (t < 16 * 32) {
            int k = 2000 + (t >> 5), bb = t & 31;
            fxA[aposKB(k, bb)] = 0;
            errA[aposKB(k, bb)] = 0;
        }
    }
    for (int i = threadIdx.x; i < NT1; i += 256) cnt[i] = 0;
    __syncthreads();
    int base = b * EPB;
    for (int e = base + threadIdx.x; e < base + EPB; e += 256)
        atomicAdd(&cnt[dst[e] >> 4], 1);
    __syncthreads();
    for (int t = threadIdx.x; t < NT1; t += 256)
        cnt_g[t * 256 + b] = cnt[t];
}

// per-tile exclusive scan over blocks; totals[t] = tile edge count
__global__ __launch_bounds__(256) void k_scan_a(const int* __restrict__ cnt_g,
                                                int* __restrict__ base_g,
                                                int* __restrict__ totals) {
    __shared__ int sh[256];
    int t = blockIdx.x, tid = threadIdx.x;
    int v = (tid < NBLK) ? cnt_g[t * 256 + tid] : 0;
    sh[tid] = v;
    __syncthreads();
    for (int off = 1; off < 256; off <<= 1) {
        int x = (tid >= off) ? sh[tid - off] : 0;
        __syncthreads();
        sh[tid] += x;
        __syncthreads();
    }
    if (tid < NBLK) base_g[t * 256 + tid] = sh[tid] - v;   // exclusive
    if (tid == 255) totals[t] = sh[255];
}

// scan tile totals -> tile_start[0..125]
__global__ void k_scan_b(const int* __restrict__ totals, int* __restrict__ tile_start) {
    if (threadIdx.x == 0 && blockIdx.x == 0) {
        int acc = 0;
        for (int t = 0; t < NT1; ++t) { tile_start[t] = acc; acc += totals[t]; }
        tile_start[NT1] = acc;
    }
}

// place edges into sorted order: pk = (bf16w<<16)|(row4<<11)|src
__global__ __launch_bounds__(256) void k_place(
        const int* __restrict__ src, const int* __restrict__ dst,
        const float* __restrict__ w, const int* __restrict__ base_g,
        const int* __restrict__ tile_start, unsigned* __restrict__ pk_g) {
    __shared__ int cur[NT1];
    int b = blockIdx.x;
    for (int t = threadIdx.x; t < NT1; t += 256)
        cur[t] = tile_start[t] + base_g[t * 256 + b];
    __syncthreads();
    int base = b * EPB;
    for (int e = base + threadIdx.x; e < base + EPB; e += 256) {
        int d = dst[e];
        unsigned pk = ((unsigned)f32_to_bf16(w[e]) << 16)
                    | ((unsigned)(d & 15) << 11) | (unsigned)src[e];
        int p = atomicAdd(&cur[d >> 4], 1);
        pk_g[p] = pk;
    }
}

// build WAbf fragments + dense bf16 WAd from sorted edges.
// 250 blocks: tile = bx>>1, half = bx&1 (rows half*8 .. half*8+7).
__global__ __launch_bounds__(256) void k_build(
        const unsigned* __restrict__ pk_g, const int* __restrict__ tile_start,
        uint4* __restrict__ WAbf4, unsigned short* __restrict__ WAd) {
    __shared__ float acc[8][KP];   // 64.5 KB
    int tile = blockIdx.x >> 1, half = blockIdx.x & 1;
    for (int i = threadIdx.x; i < 8 * KP / 4; i += 256)
        ((float4*)&acc[0][0])[i] = make_float4(0.f, 0.f, 0.f, 0.f);
    __syncthreads();
    int beg = tile_start[tile], end = tile_start[tile + 1];
    for (int e = beg + threadIdx.x; e < end; e += 256) {
        unsigned pk = pk_g[e];
        int row = (int)((pk >> 11) & 15u);
        if ((row >> 3) == half)
            atomicAdd(&acc[row & 7][pk & 0x7FFu], bf16_to_f32((unsigned short)(pk >> 16)));
    }
    __syncthreads();
    for (int i = threadIdx.x; i < 8 * 252; i += 256) {
        int rr = i / 252, g = i - rr * 252;
        int c = g >> 2, q = g & 3;
        int col = g * 8;
        unsigned short r[8];
        #pragma unroll
        for (int j = 0; j < 8; ++j) r[j] = f32_to_bf16(acc[rr][col + j]);
        uint4 val = *(const uint4*)r;
        int m = half * 8 + rr;
        WAbf4[((tile * NCH + c) * 64) + q * 16 + m] = val;
        *(uint4*)(WAd + (size_t)(tile * 16 + m) * KP + col) = val;
    }
}

// WBf[((tile*63+c)*64+l)*8+j] = WAd[c*32+(l>>4)*8+j][784+tile*16+(l&15)]
__global__ void k_trB(const unsigned short* __restrict__ WAd, uint4* __restrict__ WBf4) {
    int t = blockIdx.x * blockDim.x + threadIdx.x;
    if (t < NT2 * NCH * 64) {
        int tile = t / (NCH * 64);
        int rem = t - tile * (NCH * 64);
        int c = rem >> 6, l = rem & 63;
        int jcol = N_SENS + tile * 16 + (l & 15);
        int k0 = c * 32 + (l >> 4) * 8;
        unsigned short r[8];
        #pragma unroll
        for (int j = 0; j < 8; ++j)
            r[j] = (k0 + j < N_V) ? WAd[(size_t)(k0 + j) * KP + jcol] : (unsigned short)0;
        WBf4[t] = *(const uint4*)r;
    }
}

// coalesced init: reads vin[t] linearly; writes v_cur/fxA scattered (L2-hot);
// sensory out rows (constant across steps) written here, coalesced.
__global__ void k_init(const float* __restrict__ vin, float* __restrict__ v,
                       unsigned short* __restrict__ fxA, float* __restrict__ out) {
    int t = blockIdx.x * blockDim.x + threadIdx.x;
    if (t < NVB) {
        float x = vin[t];
        int b = t / N_V;
        int i = t - b * N_V;
        v[(i << 5) + b] = x;
        fxA[aposKB(i, b)] = f32_to_bf16(tanhf(x));
        if (i < N_SENS) out[t] = x;
    }
}

// GEMM1: err = v - fx.WA^T ; 250 blocks = 125 tiles x 2 batch-halves.
// K-loop fully unrolled (16 iters) so loads issue in parallel.
__global__ __launch_bounds__(256) void k_gemm1(
        const uint4* __restrict__ WAbf4, const uint4* __restrict__ fxA4,
        const float* __restrict__ v_cur, unsigned short* __restrict__ errA) {
    __shared__ float red[1300];
    int bx = blockIdx.x, tid = threadIdx.x;
    int w = tid >> 6, l = tid & 63;
    int tile = bx >> 1, h = bx & 1;
    int cbeg = w * 16;
    const uint4* bp = WAbf4 + (size_t)tile * NCH * 64 + cbeg * 64 + l;
    const uint4* ap = fxA4 + (size_t)h * NCH * 64 + cbeg * 64 + l;
    f32x4 acc = {0.f, 0.f, 0.f, 0.f};
    #pragma unroll
    for (int cc = 0; cc < 16; ++cc) {
        if (cbeg + cc < NCH) {
            uint4 bfrag = bp[cc * 64];
            uint4 a = ap[cc * 64];
            acc = __builtin_amdgcn_mfma_f32_16x16x32_bf16(
                      *(s16x8*)&a, *(s16x8*)&bfrag, acc, 0, 0, 0);
        }
    }
    float* my = &red[w * 325 + l * 5];
    #pragma unroll
    for (int r = 0; r < 4; ++r) my[r] = acc[r];
    __syncthreads();
    if (w == 0) {
        float s[4];
        #pragma unroll
        for (int r = 0; r < 4; ++r)
            s[r] = red[l * 5 + r] + red[325 + l * 5 + r]
                 + red[650 + l * 5 + r] + red[975 + l * 5 + r];
        int i = tile * 16 + (l & 15);
        int q = l >> 4;
        int c2 = i >> 5, q2 = (i >> 3) & 3, j2 = i & 7;
        const float4 v4 = *(const float4*)(v_cur + (i << 5) + h * 16 + q * 4);
        int base = ((h * NCH + c2) * 64 + q2 * 16) * 8 + j2;
        errA[base + (q * 4 + 0) * 8] = f32_to_bf16(v4.x - s[0]);
        errA[base + (q * 4 + 1) * 8] = f32_to_bf16(v4.y - s[1]);
        errA[base + (q * 4 + 2) * 8] = f32_to_bf16(v4.z - s[2]);
        errA[base + (q * 4 + 3) * 8] = f32_to_bf16(v4.w - s[3]);
    }
}

// GEMM2: back = err.WB^T ; 152 blocks; fused v update + tanh + fx repack;
// final: also store interior out rows.
__global__ __launch_bounds__(256) void k_gemm2(
        const uint4* __restrict__ WBf4, const uint4* __restrict__ errA4,
        unsigned short* __restrict__ errA, unsigned short* __restrict__ fxA,
        float* __restrict__ v_cur, float* __restrict__ out, int final_step) {
    __shared__ float red[1300];
    int bx = blockIdx.x, tid = threadIdx.x;
    int w = tid >> 6, l = tid & 63;
    int tile = bx >> 1, h = bx & 1;
    int cbeg = w * 16;
    const uint4* bp = WBf4 + (size_t)tile * NCH * 64 + cbeg * 64 + l;
    const uint4* ap = errA4 + (size_t)h * NCH * 64 + cbeg * 64 + l;
    f32x4 acc = {0.f, 0.f, 0.f, 0.f};
    #pragma unroll
    for (int cc = 0; cc < 16; ++cc) {
        if (cbeg + cc < NCH) {
            uint4 bfrag = bp[cc * 64];
            uint4 a = ap[cc * 64];
            acc = __builtin_amdgcn_mfma_f32_16x16x32_bf16(
                      *(s16x8*)&a, *(s16x8*)&bfrag, acc, 0, 0, 0);
        }
    }
    float* my = &red[w * 325 + l * 5];
    #pragma unroll
    for (int r = 0; r < 4; ++r) my[r] = acc[r];
    __syncthreads();
    if (w == 0) {
        float s[4];
        #pragma unroll
        for (int r = 0; r < 4; ++r)
            s[r] = red[l * 5 + r] + red[325 + l * 5 + r]
                 + red[650 + l * 5 + r] + red[975 + l * 5 + r];
        int j = N_SENS + tile * 16 + (l & 15);
        int q = l >> 4;
        int c2 = j >> 5, q2 = (j >> 3) & 3, j2 = j & 7;
        float4 v4 = *(const float4*)(v_cur + (j << 5) + h * 16 + q * 4);
        int base = ((h * NCH + c2) * 64 + q2 * 16) * 8 + j2;
        float vv[4] = {v4.x, v4.y, v4.z, v4.w};
        #pragma unroll
        for (int r = 0; r < 4; ++r) {
            float e0 = bf16_to_f32(errA[base + (q * 4 + r) * 8]);
            float fxv = tanhf(vv[r]);
            float vn = vv[r] - LR_VAL * (e0 - (1.f - fxv * fxv) * s[r]);
            vv[r] = vn;
            fxA[base + (q * 4 + r) * 8] = f32_to_bf16(tanhf(vn));
        }
        float4 o = {vv[0], vv[1], vv[2], vv[3]};
        *(float4*)(v_cur + (j << 5) + h * 16 + q * 4) = o;
        if (final_step) {
            #pragma unroll
            for (int r = 0; r < 4; ++r) {
                int b = h * 16 + q * 4 + r;
                out[b * N_V + j] = vv[r];
            }
        }
    }
}

// ------------------------- fallback path (R4 CSR, proven) ----------------

__global__ void k_zero_i32(int* a, int n) {
    int t = blockIdx.x * blockDim.x + threadIdx.x;
    if (t < n) a[t] = 0;
}

__global__ void k_hist(const int* __restrict__ src, const int* __restrict__ dst,
                       int* cnt_dst, int* cnt_src) {
    int e = blockIdx.x * blockDim.x + threadIdx.x;
    if (e < N_E) {
        atomicAdd(&cnt_dst[dst[e]], 1);
        atomicAdd(&cnt_src[src[e]], 1);
    }
}

__global__ __launch_bounds__(1024) void k_scan(int* cnt_a, int* rp_a,
                                               int* cnt_b, int* rp_b) {
    __shared__ int sh[1024];
    int t = threadIdx.x;
    for (int pass = 0; pass < 2; ++pass) {
        int* cnt = pass ? cnt_b : cnt_a;
        int* rp  = pass ? rp_b  : rp_a;
        int i0 = 2 * t, i1 = 2 * t + 1;
        int c0 = (i0 < N_V) ? cnt[i0] : 0;
        int c1 = (i1 < N_V) ? cnt[i1] : 0;
        __syncthreads();
        sh[t] = c0 + c1;
        __syncthreads();
        for (int off = 1; off < 1024; off <<= 1) {
            int v = (t >= off) ? sh[t - off] : 0;
            __syncthreads();
            sh[t] += v;
            __syncthreads();
        }
        int incl = sh[t];
        int e0 = incl - (c0 + c1);
        int e1 = e0 + c0;
        if (i0 <= N_V) rp[i0] = e0;
        if (i1 <= N_V) rp[i1] = e1;
        if (i0 < N_V) cnt[i0] = e0;
        if (i1 < N_V) cnt[i1] = e1;
    }
}

__global__ void k_scatter(const int* __restrict__ src, const int* __restrict__ dst,
                          const float* __restrict__ w,
                          int* cur_dst, int* cur_src,
                          unsigned* __restrict__ pk_dst, unsigned* __restrict__ pk_src) {
    int e = blockIdx.x * blockDim.x + threadIdx.x;
    if (e < N_E) {
        int s = src[e], d = dst[e];
        unsigned wbits = (unsigned)f32_to_bf16(w[e]);
        int p = atomicAdd(&cur_dst[d], 1);
        pk_dst[p] = (wbits << 16) | (unsigned)s;
        int q = atomicAdd(&cur_src[s], 1);
        pk_src[q] = (wbits << 16) | (unsigned)d;
    }
}

__global__ void k_cast_in(const float* __restrict__ vin, float* __restrict__ v) {
    int t = blockIdx.x * blockDim.x + threadIdx.x;
    if (t < NVB) {
        int i = t >> 5, b = t & 31;
        v[t] = vin[b * N_V + i];
    }
}

__global__ void k_fx_csr(const float* __restrict__ v, unsigned short* __restrict__ fx) {
    int t = blockIdx.x * blockDim.x + threadIdx.x;
    if (t < NVB) {
        int i = t >> 5, b = t & 31;
        int h = b >> 4, b16 = b & 15;
        fx[h * NVH + i * 16 + b16] = f32_to_bf16(tanhf(v[t]));
    }
}

__global__ __launch_bounds__(256) void k_pred_err(
        const float* __restrict__ v, const unsigned short* __restrict__ fx,
        const int* __restrict__ rp, const unsigned* __restrict__ pk,
        unsigned short* __restrict__ err) {
    __shared__ unsigned short tab[NVH];
    int h  = blockIdx.x / 250;
    int vg = blockIdx.x % 250;
    {
        const uint4* g = (const uint4*)(fx + h * NVH);
        uint4* l = (uint4*)tab;
        for (int i = threadIdx.x; i < NVH / 8; i += 256) l[i] = g[i];
    }
    __syncthreads();
    int wave = threadIdx.x >> 6;
    int lane = threadIdx.x & 63;
    int b16 = lane & 15, epar = lane >> 4;
    for (int k = 0; k < 2; ++k) {
        int vid = vg * 8 + wave * 2 + k;
        int beg = rp[vid], end = rp[vid + 1];
        float sum = 0.f;
        for (int e = beg + epar; e < end; e += 4) {
            unsigned p = pk[e];
            float w = bits_to_f32(p & 0xFFFF0000u);
            int nb = (int)(p & 0xFFFFu);
            sum += w * bf16_to_f32(tab[nb * 16 + b16]);
        }
        sum += __shfl_xor(sum, 16, 64);
        sum += __shfl_xor(sum, 32, 64);
        if (epar == 0) {
            float vo = v[(vid << 5) + h * 16 + b16];
            err[h * NVH + vid * 16 + b16] = f32_to_bf16(vo - sum);
        }
    }
}

__global__ __launch_bounds__(256) void k_back_upd(
        const unsigned short* __restrict__ fx, const unsigned short* __restrict__ err,
        const int* __restrict__ rp, const unsigned* __restrict__ pk,
        float* __restrict__ v) {
    __shared__ unsigned short tab[NVH];
    int h  = blockIdx.x / 152;
    int vg = blockIdx.x % 152;
    {
        const uint4* g = (const uint4*)(err + h * NVH);
        uint4* l = (uint4*)tab;
        for (int i = threadIdx.x; i < NVH / 8; i += 256) l[i] = g[i];
    }
    __syncthreads();
    int wave = threadIdx.x >> 6;
    int lane = threadIdx.x & 63;
    int b16 = lane & 15, epar = lane >> 4;
    for (int k = 0; k < 2; ++k) {
        int vid = N_SENS + vg * 8 + wave * 2 + k;
        if (vid >= N_V) continue;
        int beg = rp[vid], end = rp[vid + 1];
        float sum = 0.f;
        for (int e = beg + epar; e < end; e += 4) {
            unsigned p = pk[e];
            float w = bits_to_f32(p & 0xFFFF0000u);
            int nb = (int)(p & 0xFFFFu);
            sum += w * bf16_to_f32(tab[nb * 16 + b16]);
        }
        sum += __shfl_xor(sum, 16, 64);
        sum += __shfl_xor(sum, 32, 64);
        if (epar == 0) {
            float e0  = bf16_to_f32(tab[vid * 16 + b16]);
            float fxv = bf16_to_f32(fx[h * NVH + vid * 16 + b16]);
            float dv = e0 - (1.f - fxv * fxv) * sum;
            v[(vid << 5) + h * 16 + b16] -= LR_VAL * dv;
        }
    }
}

__global__ void k_out_fb(const float* __restrict__ v, float* __restrict__ out) {
    int t = blockIdx.x * blockDim.x + threadIdx.x;
    if (t < NVB) {
        int b = t / N_V;
        int i = t - b * N_V;
        out[t] = v[(i << 5) + b];
    }
}

// ------------------------- host -----------------------------------------

extern "C" void kernel_launch(void* const* d_in, const int* in_sizes, int n_in,
                              void* d_out, int out_size, void* d_ws, size_t ws_size,
                              hipStream_t stream) {
    const float* vals = (const float*)d_in[0];
    const float* wts  = (const float*)d_in[1];
    const int* ei = (const int*)d_in[2];
    const int* src = ei;
    const int* dst = ei + N_E;
    float* out = (float*)d_out;

    const int EB = (N_E + 255) / 256;

    // ws layout: pk_g | cnt_g | base_g | totals | tile_start | WAd | WAbf | WBf
    //            | fxA | errA | v_cur   (~23.5 MB)
    const size_t WABF_T = (size_t)NT1 * NCH * 64;  // uint4 count
    const size_t WBF_T  = (size_t)NT2 * NCH * 64;
    const size_t WAD_N  = (size_t)N_V * KP;
    const size_t need = (size_t)N_E * 4 + 2 * NT1 * 256 * 4 + 512 * 4
                      + WAD_N * 2 + WABF_T * 16 + WBF_T * 16
                      + 2 * (size_t)FRAG_N * 2 + NVB * 4 + 256;

    if (ws_size >= need) {
        unsigned* pk_g = (unsigned*)d_ws;
        int* cnt_g  = (int*)(pk_g + N_E);
        int* base_g = cnt_g + NT1 * 256;
        int* totals = base_g + NT1 * 256;
        int* tile_start = totals + 128;
        unsigned short* WAd = (unsigned short*)(tile_start + 384);
        uint4* WAbf4 = (uint4*)(WAd + WAD_N);
        uint4* WBf4  = WAbf4 + WABF_T;
        unsigned short* fxA  = (unsigned short*)(WBf4 + WBF_T);
        unsigned short* errA = fxA + FRAG_N;
        float* v_cur = (float*)(errA + FRAG_N);

        k_cnt<<<NBLK, 256, 0, stream>>>(dst, cnt_g, fxA, errA);
        k_scan_a<<<NT1, 256, 0, stream>>>(cnt_g, base_g, totals);
        k_scan_b<<<1, 64, 0, stream>>>(totals, tile_start);
        k_place<<<NBLK, 256, 0, stream>>>(src, dst, wts, base_g, tile_start, pk_g);
        k_build<<<2 * NT1, 256, 0, stream>>>(pk_g, tile_start, WAbf4, WAd);
        k_trB<<<(int)((WBF_T + 255) / 256), 256, 0, stream>>>(WAd, WBf4);
        k_init<<<250, 256, 0, stream>>>(vals, v_cur, fxA, out);

        for (int t = 0; t < T_STEPS; ++t) {
            k_gemm1<<<250, 256, 0, stream>>>(WAbf4, (const uint4*)fxA, v_cur, errA);
            k_gemm2<<<152, 256, 0, stream>>>(WBf4, (const uint4*)errA, errA, fxA,
                                             v_cur, out, (t == T_STEPS - 1) ? 1 : 0);
        }
    } else {
        float* v_cur = (float*)d_ws;
        unsigned short* fx_g  = (unsigned short*)(v_cur + NVB);
        unsigned short* err_g = fx_g + NVB;
        int* rp_dst  = (int*)(err_g + NVB);
        int* rp_src  = rp_dst + 2048;
        int* cur_dst = rp_src + 2048;
        int* cur_src = cur_dst + 2048;
        unsigned* pk_dst = (unsigned*)(cur_src + 2048);
        unsigned* pk_src = pk_dst + N_E;

        k_zero_i32<<<16, 256, 0, stream>>>(cur_dst, 4096);
        k_hist<<<EB, 256, 0, stream>>>(src, dst, cur_dst, cur_src);
        k_scan<<<1, 1024, 0, stream>>>(cur_dst, rp_dst, cur_src, rp_src);
        k_scatter<<<EB, 256, 0, stream>>>(src, dst, wts, cur_dst, cur_src,
                                          pk_dst, pk_src);
        k_cast_in<<<250, 256, 0, stream>>>(vals, v_cur);
        for (int t = 0; t < T_STEPS; ++t) {
            k_fx_csr<<<250, 256, 0, stream>>>(v_cur, fx_g);
            k_pred_err<<<500, 256, 0, stream>>>(v_cur, fx_g, rp_dst, pk_dst, err_g);
            k_back_upd<<<304, 256, 0, stream>>>(fx_g, err_g, rp_src, pk_src, v_cur);
        }
        k_out_fb<<<250, 256, 0, stream>>>(v_cur, out);
    }
}